// Round 15
// baseline (145.907 us; speedup 1.0000x reference)
//
#include <hip/hip_runtime.h>

typedef __attribute__((ext_vector_type(8))) short short8;
typedef __attribute__((ext_vector_type(16))) float f32x16;
typedef __attribute__((ext_vector_type(4))) float f32x4;

#define L2T 13.287712379549449f  // log2(10000)

__device__ __forceinline__ unsigned short f2bf(float f) {
  unsigned int u = __float_as_uint(f);
  u += 0x7FFFu + ((u >> 16) & 1u);
  return (unsigned short)(u >> 16);
}
__device__ __forceinline__ float bf2f(unsigned short u) {
  return __uint_as_float(((unsigned int)u) << 16);
}

// async global->LDS, 16B per lane; LDS dest = wave-uniform base + lane*16
__device__ __forceinline__ void gload16(const unsigned short* g, unsigned short* l) {
  __builtin_amdgcn_global_load_lds(
      (const __attribute__((address_space(1))) void*)g,
      (__attribute__((address_space(3))) void*)l, 16, 0, 0);
}

// ---------------- prep: cast x fp32->bf16 (blocks 0..12287) + transpose w (rest) -------
__global__ __launch_bounds__(256) void prep_kernel(const float* __restrict__ x,
                                                   unsigned short* __restrict__ xb,
                                                   const float* __restrict__ w,
                                                   unsigned short* __restrict__ wt) {
  __shared__ float tile[32][33];
  int bid = blockIdx.x;
  if (bid < 12288) {
    int i = bid * 256 + threadIdx.x;
    float4 v = ((const float4*)x)[i];
    ushort4 o;
    o.x = f2bf(v.x); o.y = f2bf(v.y); o.z = f2bf(v.z); o.w = f2bf(v.w);
    ((ushort4*)xb)[i] = o;
  } else {
    int b2 = bid - 12288;               // 0..1727
    int n0 = (b2 % 72) * 32, k0 = (b2 / 72) * 32;
    int tx = threadIdx.x & 31, ty = threadIdx.x >> 5;
    for (int i = ty; i < 32; i += 8)
      tile[i][tx] = w[(size_t)(k0 + i) * 2304 + n0 + tx];
    __syncthreads();
    for (int i = ty; i < 32; i += 8)
      wt[(size_t)(n0 + i) * 768 + k0 + tx] = f2bf(tile[tx][i]);
  }
}

// ---------------- QKV GEMM: gload_lds(16B) + BK=64 + XOR swizzle + fused RoPE ----------
// RoPE via block-local LDS cos/sin table (reuses lA post-loop): 8 cooperative sincos
// per thread replace ~21 serial per-element sincos in the tail; epilogue reads are
// ds_read_b64. Same __sincosf inputs -> bitwise-identical output to R13.
__global__ __launch_bounds__(256) void qkv_gemm_kernel(
    const unsigned short* __restrict__ xb,
    const unsigned short* __restrict__ wt,
    const float* __restrict__ bias,
    unsigned short* __restrict__ Qb,
    unsigned short* __restrict__ Kb,
    unsigned short* __restrict__ Vb) {
  __shared__ __attribute__((aligned(16))) unsigned short lA[128 * 64];
  __shared__ __attribute__((aligned(16))) unsigned short lB[128 * 64];
  // XCD swizzle: 2304 blocks, 2304%8==0 -> bijective chunked remap (T1)
  int bid = blockIdx.x;
  int swz = (bid & 7) * 288 + (bid >> 3);
  int mt = swz / 18, nt = swz - mt * 18;
  int m0 = mt * 128, n0 = nt * 128;

  int tid = threadIdx.x;
  int lane = tid & 63, wid = tid >> 6;
  int wr = wid >> 1, wc = wid & 1;
  int lr = lane & 15, lg = lane >> 4;
  int lswz = lr & 7;

  int offA[4], offB[4];
  unsigned short* ldsA[4];
  unsigned short* ldsB[4];
#pragma unroll
  for (int i = 0; i < 4; i++) {
    int gi = (wid * 4 + i) * 64 + lane;  // granule id in tile
    int r = gi >> 3;                     // row 0..127
    int gcl = (gi & 7) ^ (r & 7);        // pre-swizzled source col-granule
    offA[i] = (m0 + r) * 768 + gcl * 8;
    offB[i] = (n0 + r) * 768 + gcl * 8;
    ldsA[i] = &lA[(wid * 4 + i) * 512];
    ldsB[i] = &lB[(wid * 4 + i) * 512];
  }

  f32x4 acc[4][4] = {};
  const int rowA = (wr * 64 + lr) * 64;
  const int rowB = (wc * 64 + lr) * 64;

  for (int k0 = 0; k0 < 768; k0 += 64) {
    __syncthreads();
#pragma unroll
    for (int i = 0; i < 4; i++) gload16(xb + offA[i] + k0, ldsA[i]);
#pragma unroll
    for (int i = 0; i < 4; i++) gload16(wt + offB[i] + k0, ldsB[i]);
    __syncthreads();

    short8 af[4][2], bfr[4][2];
#pragma unroll
    for (int ks = 0; ks < 2; ks++) {
      int c = ((ks * 4 + lg) ^ lswz) * 8;
#pragma unroll
      for (int mi = 0; mi < 4; mi++)
        af[mi][ks] = *(const short8*)(&lA[rowA + mi * 1024 + c]);
#pragma unroll
      for (int ni = 0; ni < 4; ni++)
        bfr[ni][ks] = *(const short8*)(&lB[rowB + ni * 1024 + c]);
    }
#pragma unroll
    for (int ks = 0; ks < 2; ks++)
#pragma unroll
      for (int mi = 0; mi < 4; mi++)
#pragma unroll
        for (int ni = 0; ni < 4; ni++)
          acc[mi][ni] = __builtin_amdgcn_mfma_f32_16x16x32_bf16(af[mi][ks], bfr[ni][ks], acc[mi][ni], 0, 0, 0);
  }

  // build block-local cos/sin table in lA (16 KB): tbl[ml*16+j] for t = m0+ml
  __syncthreads();  // all waves' LDS reads complete (lgkmcnt drained before last MFMAs)
  float2* tbl = (float2*)lA;
  {
    int i = tid;
#pragma unroll
    for (int it = 0; it < 8; it++, i += 256) {
      int ml = i >> 4, j = i & 15;
      int t = (m0 + ml) & 4095;
      float invf = exp2f(-(float)j * (L2T / 16.0f));
      float ang = (float)t * invf;
      float s, c;
      __sincosf(ang, &s, &c);
      tbl[i] = make_float2(c, s);
    }
  }
  __syncthreads();

  // epilogue: bias + RoPE (table lookup) + 1/8 scale on q, scatter head-major
#pragma unroll
  for (int ni = 0; ni < 4; ni++) {
    int n = n0 + wc * 64 + ni * 16 + lr;
    float bv = bias[n];
    int which = n / 768;       // 0=q 1=k 2=v (uniform across lanes here)
    int idx = n - which * 768;
    int h = idx >> 6, d = idx & 63;
    float scl = (which == 0) ? 0.125f : 1.0f;
    bool doRope = (which < 2) && (ni < 2);  // d<32  <=>  ni<2 (uniform)
    bool isHi = (d & 1);
    int j = (d >> 1) & 15;
    unsigned short* dst = (which == 0) ? Qb : ((which == 1) ? Kb : Vb);
#pragma unroll
    for (int mi = 0; mi < 4; mi++) {
#pragma unroll
      for (int reg = 0; reg < 4; reg++) {
        int ml = wr * 64 + mi * 16 + lg * 4 + reg;
        int m = m0 + ml;
        int b = m >> 12, t = m & 4095;
        float val = acc[mi][ni][reg] + bv;
        if (doRope) {  // uniform branch; pair partner is lane lr^1 (same mi,ni,reg)
          float other = __shfl_xor(val, 1, 64);
          float2 cs = tbl[ml * 16 + j];
          val = isHi ? (val * cs.x + other * cs.y) : (val * cs.x - other * cs.y);
        }
        dst[(((size_t)(b * 12 + h)) * 4096 + t) * 64 + d] = f2bf(val * scl);
      }
    }
  }
}

// ---------------- sliding-window attention, 32x32 MFMA (R13 body, byte-exact) -----------
#define KV_S 72
__global__ __launch_bounds__(256) void attn_kernel(
    const unsigned short* __restrict__ Qb,
    const unsigned short* __restrict__ Kb,
    const unsigned short* __restrict__ Vb,
    float* __restrict__ out) {
  __shared__ unsigned short kS[64 * KV_S];  // [key][dim]
  __shared__ unsigned short vS[64 * KV_S];  // [dim][key]
  int bidx = blockIdx.x;
  int wi = ((bidx & 7) << 2) | (bidx >> 3);  // bijective window remap (L2 locality)
  int bh = blockIdx.y;
  int b = bh / 12, h = bh - b * 12;
  int tid = threadIdx.x, lane = tid & 63, wid = tid >> 6;
  int l31 = lane & 31, hi = lane >> 5;

  int qb0 = wi * 128 + wid * 32;
  const unsigned short* Qrow = Qb + ((size_t)bh * 4096 + qb0) * 64;
  short8 qf[4];
#pragma unroll
  for (int kk = 0; kk < 4; kk++)
    qf[kk] = *(const short8*)(Qrow + (size_t)l31 * 64 + kk * 16 + hi * 8);

  f32x16 oacc[2];
#pragma unroll
  for (int dt = 0; dt < 2; dt++)
#pragma unroll
    for (int r = 0; r < 16; r++) oacc[dt][r] = 0.0f;
  float mrow = -1e30f, lsum = 0.0f;

  const unsigned short* Kbase = Kb + (size_t)bh * 4096 * 64;
  const unsigned short* Vbase = Vb + (size_t)bh * 4096 * 64;

  int vk = tid & 63;
  int vq = tid >> 6;

  for (int c = 0; c < 6; c++) {
    int kp0 = (wi - 1) * 128 + c * 64;
    if (kp0 < 0 || kp0 >= 4096) continue;

    __syncthreads();
#pragma unroll
    for (int ci = tid; ci < 512; ci += 256) {
      int kk = ci >> 3, co = (ci & 7) * 8;
      *(uint4*)(&kS[kk * KV_S + co]) = *(const uint4*)(Kbase + (size_t)(kp0 + kk) * 64 + co);
    }
    {
      const unsigned short* vp = Vbase + (size_t)(kp0 + vk) * 64 + vq * 16;
      uint4 v0 = *(const uint4*)(vp);
      uint4 v1 = *(const uint4*)(vp + 8);
      const unsigned short* e = (const unsigned short*)&v0;
#pragma unroll
      for (int i = 0; i < 8; i++) vS[(vq * 16 + i) * KV_S + vk] = e[i];
      e = (const unsigned short*)&v1;
#pragma unroll
      for (int i = 0; i < 8; i++) vS[(vq * 16 + 8 + i) * KV_S + vk] = e[i];
    }
    __syncthreads();

    f32x16 s[2];
#pragma unroll
    for (int kt = 0; kt < 2; kt++) {
      f32x16 acc;
#pragma unroll
      for (int r = 0; r < 16; r++) acc[r] = 0.0f;
#pragma unroll
      for (int kk = 0; kk < 4; kk++) {
        short8 kf = *(const short8*)(&kS[(kt * 32 + l31) * KV_S + kk * 16 + hi * 8]);
        acc = __builtin_amdgcn_mfma_f32_32x32x16_bf16(kf, qf[kk], acc, 0, 0, 0);
      }
      s[kt] = acc;
    }

    float vmax = -1e30f;
#pragma unroll
    for (int kt = 0; kt < 2; kt++)
#pragma unroll
      for (int r = 0; r < 16; r++) vmax = fmaxf(vmax, s[kt][r]);
    vmax = fmaxf(vmax, __shfl_xor(vmax, 32, 64));
    float mnew = fmaxf(mrow, vmax);
    float corr = __expf(mrow - mnew);
    mrow = mnew;
    float rs = 0.0f;
#pragma unroll
    for (int kt = 0; kt < 2; kt++)
#pragma unroll
      for (int r = 0; r < 16; r++) {
        float p = __expf(s[kt][r] - mnew);
        s[kt][r] = p;
        rs += p;
      }
    rs += __shfl_xor(rs, 32, 64);
    lsum = lsum * corr + rs;
#pragma unroll
    for (int dt = 0; dt < 2; dt++)
#pragma unroll
      for (int r = 0; r < 16; r++) oacc[dt][r] *= corr;

#pragma unroll
    for (int kt = 0; kt < 2; kt++) {
#pragma unroll
      for (int kk = 0; kk < 2; kk++) {
        unsigned a0, a1, b0, b1;
        asm("v_cvt_pk_bf16_f32 %0, %1, %2" : "=v"(a0) : "v"(s[kt][kk * 8 + 0]), "v"(s[kt][kk * 8 + 1]));
        asm("v_cvt_pk_bf16_f32 %0, %1, %2" : "=v"(a1) : "v"(s[kt][kk * 8 + 2]), "v"(s[kt][kk * 8 + 3]));
        asm("v_cvt_pk_bf16_f32 %0, %1, %2" : "=v"(b0) : "v"(s[kt][kk * 8 + 4]), "v"(s[kt][kk * 8 + 5]));
        asm("v_cvt_pk_bf16_f32 %0, %1, %2" : "=v"(b1) : "v"(s[kt][kk * 8 + 6]), "v"(s[kt][kk * 8 + 7]));
        asm("v_permlane32_swap_b32 %0, %1" : "+v"(a0), "+v"(b0));
        asm("v_permlane32_swap_b32 %0, %1" : "+v"(a1), "+v"(b1));
        union { unsigned u[4]; short8 v; } pb;
        pb.u[0] = a0; pb.u[1] = a1; pb.u[2] = b0; pb.u[3] = b1;
#pragma unroll
        for (int dt = 0; dt < 2; dt++) {
          short8 vf = *(const short8*)(&vS[(dt * 32 + l31) * KV_S + kt * 32 + kk * 16 + hi * 8]);
          oacc[dt] = __builtin_amdgcn_mfma_f32_32x32x16_bf16(vf, pb.v, oacc[dt], 0, 0, 0);
        }
      }
    }
  }

  float inv = 1.0f / lsum;
  float* orow = out + ((size_t)b * 4096 + qb0 + l31) * 768 + h * 64;
#pragma unroll
  for (int dt = 0; dt < 2; dt++)
#pragma unroll
    for (int g = 0; g < 4; g++) {
      float4 o;
      o.x = oacc[dt][g * 4 + 0] * inv;
      o.y = oacc[dt][g * 4 + 1] * inv;
      o.z = oacc[dt][g * 4 + 2] * inv;
      o.w = oacc[dt][g * 4 + 3] * inv;
      *(float4*)(orow + dt * 32 + g * 8 + hi * 4) = o;
    }
}

extern "C" void kernel_launch(void* const* d_in, const int* in_sizes, int n_in,
                              void* d_out, int out_size, void* d_ws, size_t ws_size,
                              hipStream_t stream) {
  const float* x = (const float*)d_in[0];      // 4 x 4096 x 768
  const float* w = (const float*)d_in[1];      // 768 x 2304
  const float* bias = (const float*)d_in[2];   // 2304
  float* out = (float*)d_out;                  // 4 x 4096 x 768 fp32

  char* ws = (char*)d_ws;
  unsigned short* xb = (unsigned short*)ws;                       // 16384x768 bf16
  unsigned short* wt = (unsigned short*)(ws + 25165824);          // 2304x768 bf16
  unsigned short* Qb = (unsigned short*)(ws + 28704768);
  unsigned short* Kb = Qb + 12582912;
  unsigned short* Vb = Kb + 12582912;

  hipLaunchKernelGGL(prep_kernel, dim3(14016), dim3(256), 0, stream, x, xb, w, wt);
  hipLaunchKernelGGL(qkv_gemm_kernel, dim3(2304), dim3(256), 0, stream, xb, wt, bias, Qb, Kb, Vb);
  hipLaunchKernelGGL(attn_kernel, dim3(32, 48), dim3(256), 0, stream, Qb, Kb, Vb, out);
}

// Round 16
// 127.297 us; speedup vs baseline: 1.1462x; 1.1462x over previous
//
#include <hip/hip_runtime.h>

typedef __attribute__((ext_vector_type(8))) short short8;
typedef __attribute__((ext_vector_type(16))) float f32x16;
typedef __attribute__((ext_vector_type(4))) float f32x4;

#define L2T 13.287712379549449f  // log2(10000)

__device__ __forceinline__ unsigned short f2bf(float f) {
  unsigned int u = __float_as_uint(f);
  u += 0x7FFFu + ((u >> 16) & 1u);
  return (unsigned short)(u >> 16);
}
__device__ __forceinline__ float bf2f(unsigned short u) {
  return __uint_as_float(((unsigned int)u) << 16);
}

// async global->LDS, 16B per lane; LDS dest = wave-uniform base + lane*16
__device__ __forceinline__ void gload16(const unsigned short* g, unsigned short* l) {
  __builtin_amdgcn_global_load_lds(
      (const __attribute__((address_space(1))) void*)g,
      (__attribute__((address_space(3))) void*)l, 16, 0, 0);
}

// ---------------- prep: cast x fp32->bf16 (blocks 0..12287) + transpose w (rest) -------
__global__ __launch_bounds__(256) void prep_kernel(const float* __restrict__ x,
                                                   unsigned short* __restrict__ xb,
                                                   const float* __restrict__ w,
                                                   unsigned short* __restrict__ wt) {
  __shared__ float tile[32][33];
  int bid = blockIdx.x;
  if (bid < 12288) {
    int i = bid * 256 + threadIdx.x;
    float4 v = ((const float4*)x)[i];
    ushort4 o;
    o.x = f2bf(v.x); o.y = f2bf(v.y); o.z = f2bf(v.z); o.w = f2bf(v.w);
    ((ushort4*)xb)[i] = o;
  } else {
    int b2 = bid - 12288;               // 0..1727
    int n0 = (b2 % 72) * 32, k0 = (b2 / 72) * 32;
    int tx = threadIdx.x & 31, ty = threadIdx.x >> 5;
    for (int i = ty; i < 32; i += 8)
      tile[i][tx] = w[(size_t)(k0 + i) * 2304 + n0 + tx];
    __syncthreads();
    for (int i = ty; i < 32; i += 8)
      wt[(size_t)(n0 + i) * 768 + k0 + tx] = f2bf(tile[tx][i]);
  }
}

// ---------------- QKV GEMM: gload_lds(16B) + BK=64 + XOR swizzle -----------------------
// Tail: bias for all; RoPE only for K (which==1, d<32) — Q rope/scale moved to attn.
// Epilogue loop order (mi,reg) outer / ni inner: the 4 stores sharing one 128B output
// line (same h,t; d=ni*16+lr) are adjacent -> write combining (was 96MB, ideal 75MB).
__global__ __launch_bounds__(256) void qkv_gemm_kernel(
    const unsigned short* __restrict__ xb,
    const unsigned short* __restrict__ wt,
    const float* __restrict__ bias,
    unsigned short* __restrict__ Qb,
    unsigned short* __restrict__ Kb,
    unsigned short* __restrict__ Vb) {
  __shared__ unsigned short lA[128 * 64];
  __shared__ unsigned short lB[128 * 64];
  // XCD swizzle: 2304 blocks, 2304%8==0 -> bijective chunked remap (T1)
  int bid = blockIdx.x;
  int swz = (bid & 7) * 288 + (bid >> 3);
  int mt = swz / 18, nt = swz - mt * 18;
  int m0 = mt * 128, n0 = nt * 128;

  int tid = threadIdx.x;
  int lane = tid & 63, wid = tid >> 6;
  int wr = wid >> 1, wc = wid & 1;
  int lr = lane & 15, lg = lane >> 4;
  int lswz = lr & 7;

  int offA[4], offB[4];
  unsigned short* ldsA[4];
  unsigned short* ldsB[4];
#pragma unroll
  for (int i = 0; i < 4; i++) {
    int gi = (wid * 4 + i) * 64 + lane;  // granule id in tile
    int r = gi >> 3;                     // row 0..127
    int gcl = (gi & 7) ^ (r & 7);        // pre-swizzled source col-granule
    offA[i] = (m0 + r) * 768 + gcl * 8;
    offB[i] = (n0 + r) * 768 + gcl * 8;
    ldsA[i] = &lA[(wid * 4 + i) * 512];
    ldsB[i] = &lB[(wid * 4 + i) * 512];
  }

  f32x4 acc[4][4] = {};
  const int rowA = (wr * 64 + lr) * 64;
  const int rowB = (wc * 64 + lr) * 64;

  for (int k0 = 0; k0 < 768; k0 += 64) {
    __syncthreads();
#pragma unroll
    for (int i = 0; i < 4; i++) gload16(xb + offA[i] + k0, ldsA[i]);
#pragma unroll
    for (int i = 0; i < 4; i++) gload16(wt + offB[i] + k0, ldsB[i]);
    __syncthreads();

    short8 af[4][2], bfr[4][2];
#pragma unroll
    for (int ks = 0; ks < 2; ks++) {
      int c = ((ks * 4 + lg) ^ lswz) * 8;
#pragma unroll
      for (int mi = 0; mi < 4; mi++)
        af[mi][ks] = *(const short8*)(&lA[rowA + mi * 1024 + c]);
#pragma unroll
      for (int ni = 0; ni < 4; ni++)
        bfr[ni][ks] = *(const short8*)(&lB[rowB + ni * 1024 + c]);
    }
#pragma unroll
    for (int ks = 0; ks < 2; ks++)
#pragma unroll
      for (int mi = 0; mi < 4; mi++)
#pragma unroll
        for (int ni = 0; ni < 4; ni++)
          acc[mi][ni] = __builtin_amdgcn_mfma_f32_16x16x32_bf16(af[mi][ks], bfr[ni][ks], acc[mi][ni], 0, 0, 0);
  }

  // epilogue
  int nb = n0 + wc * 64 + lr;          // ni adds 16
  int which = nb / 768;                 // uniform across lanes and ni
  int idx = nb - which * 768;
  int h = idx >> 6;
  int dbase = idx & 63;                 // d = dbase + ni*16; dbase = lr here
  unsigned short* dst = (which == 0) ? Qb : ((which == 1) ? Kb : Vb);
  bool kv = (which == 1);
  bool isHi = dbase & 1;
  float bvv[4], cinv[4];
#pragma unroll
  for (int ni = 0; ni < 4; ni++) {
    bvv[ni] = bias[nb + ni * 16];
    cinv[ni] = exp2f(-(float)(((dbase + ni * 16) >> 1) & 15) * (L2T / 16.0f));
  }
#pragma unroll
  for (int mi = 0; mi < 4; mi++) {
#pragma unroll
    for (int reg = 0; reg < 4; reg++) {
      int m = m0 + wr * 64 + mi * 16 + lg * 4 + reg;
      int b = m >> 12, t = m & 4095;
      size_t rowoff = (((size_t)(b * 12 + h)) * 4096 + t) * 64;
#pragma unroll
      for (int ni = 0; ni < 4; ni++) {
        float val = acc[mi][ni][reg] + bvv[ni];
        if (kv && ni < 2) {  // K rope, d<32; wave-uniform; partner lane lr^1
          float other = __shfl_xor(val, 1, 64);
          float ang = (float)t * cinv[ni];
          float s, c;
          __sincosf(ang, &s, &c);
          val = isHi ? (val * c + other * s) : (val * c - other * s);
        }
        dst[rowoff + dbase + ni * 16] = f2bf(val);
      }
    }
  }
}

// ---------------- sliding-window attention (R14 body byte-exact: Q-rope + post-scale) ---
#define KV_S 72
__global__ __launch_bounds__(256) void attn_kernel(
    const unsigned short* __restrict__ Qb,
    const unsigned short* __restrict__ Kb,
    const unsigned short* __restrict__ Vb,
    float* __restrict__ out) {
  __shared__ unsigned short kS[64 * KV_S];  // [key][dim]
  __shared__ unsigned short vS[64 * KV_S];  // [dim][key]
  int bidx = blockIdx.x;
  int wi = ((bidx & 7) << 2) | (bidx >> 3);  // bijective window remap (L2 locality)
  int bh = blockIdx.y;
  int b = bh / 12, h = bh - b * 12;
  int tid = threadIdx.x, lane = tid & 63, wid = tid >> 6;
  int l31 = lane & 31, hi = lane >> 5;

  int qb0 = wi * 128 + wid * 32;
  const unsigned short* Qrow = Qb + ((size_t)bh * 4096 + qb0) * 64;
  short8 qf[4];
#pragma unroll
  for (int kk = 0; kk < 4; kk++)
    qf[kk] = *(const short8*)(Qrow + (size_t)l31 * 64 + kk * 16 + hi * 8);

  // RoPE on Q frags kk=0,1 (dims<32); pairs in-lane; t = qb0 + l31 (R11/R14-proven)
  {
    int t = qb0 + l31;
#pragma unroll
    for (int kk = 0; kk < 2; kk++) {
      unsigned short* e = (unsigned short*)&qf[kk];
      int j0 = kk * 8 + hi * 4;
#pragma unroll
      for (int p = 0; p < 4; p++) {
        float invf = exp2f(-(float)(j0 + p) * (L2T / 16.0f));
        float ang = (float)t * invf;
        float s, c;
        __sincosf(ang, &s, &c);
        float a = bf2f(e[2 * p]), b2 = bf2f(e[2 * p + 1]);
        e[2 * p] = f2bf(a * c - b2 * s);
        e[2 * p + 1] = f2bf(b2 * c + a * s);
      }
    }
  }

  f32x16 oacc[2];
#pragma unroll
  for (int dt = 0; dt < 2; dt++)
#pragma unroll
    for (int r = 0; r < 16; r++) oacc[dt][r] = 0.0f;
  float mrow = -1e30f, lsum = 0.0f;

  const unsigned short* Kbase = Kb + (size_t)bh * 4096 * 64;
  const unsigned short* Vbase = Vb + (size_t)bh * 4096 * 64;

  int vk = tid & 63;
  int vq = tid >> 6;

  for (int c = 0; c < 6; c++) {
    int kp0 = (wi - 1) * 128 + c * 64;
    if (kp0 < 0 || kp0 >= 4096) continue;

    __syncthreads();
#pragma unroll
    for (int ci = tid; ci < 512; ci += 256) {
      int kk = ci >> 3, co = (ci & 7) * 8;
      *(uint4*)(&kS[kk * KV_S + co]) = *(const uint4*)(Kbase + (size_t)(kp0 + kk) * 64 + co);
    }
    {
      const unsigned short* vp = Vbase + (size_t)(kp0 + vk) * 64 + vq * 16;
      uint4 v0 = *(const uint4*)(vp);
      uint4 v1 = *(const uint4*)(vp + 8);
      const unsigned short* e = (const unsigned short*)&v0;
#pragma unroll
      for (int i = 0; i < 8; i++) vS[(vq * 16 + i) * KV_S + vk] = e[i];
      e = (const unsigned short*)&v1;
#pragma unroll
      for (int i = 0; i < 8; i++) vS[(vq * 16 + 8 + i) * KV_S + vk] = e[i];
    }
    __syncthreads();

    f32x16 s[2];
#pragma unroll
    for (int kt = 0; kt < 2; kt++) {
      f32x16 acc;
#pragma unroll
      for (int r = 0; r < 16; r++) acc[r] = 0.0f;
#pragma unroll
      for (int kk = 0; kk < 4; kk++) {
        short8 kf = *(const short8*)(&kS[(kt * 32 + l31) * KV_S + kk * 16 + hi * 8]);
        acc = __builtin_amdgcn_mfma_f32_32x32x16_bf16(kf, qf[kk], acc, 0, 0, 0);
      }
      s[kt] = acc;
    }
    // 1/8 softmax scale post-MFMA (R11/R14-proven exact)
#pragma unroll
    for (int kt = 0; kt < 2; kt++)
#pragma unroll
      for (int r = 0; r < 16; r++) s[kt][r] *= 0.125f;

    float vmax = -1e30f;
#pragma unroll
    for (int kt = 0; kt < 2; kt++)
#pragma unroll
      for (int r = 0; r < 16; r++) vmax = fmaxf(vmax, s[kt][r]);
    vmax = fmaxf(vmax, __shfl_xor(vmax, 32, 64));
    float mnew = fmaxf(mrow, vmax);
    float corr = __expf(mrow - mnew);
    mrow = mnew;
    float rs = 0.0f;
#pragma unroll
    for (int kt = 0; kt < 2; kt++)
#pragma unroll
      for (int r = 0; r < 16; r++) {
        float p = __expf(s[kt][r] - mnew);
        s[kt][r] = p;
        rs += p;
      }
    rs += __shfl_xor(rs, 32, 64);
    lsum = lsum * corr + rs;
#pragma unroll
    for (int dt = 0; dt < 2; dt++)
#pragma unroll
      for (int r = 0; r < 16; r++) oacc[dt][r] *= corr;

#pragma unroll
    for (int kt = 0; kt < 2; kt++) {
#pragma unroll
      for (int kk = 0; kk < 2; kk++) {
        unsigned a0, a1, b0, b1;
        asm("v_cvt_pk_bf16_f32 %0, %1, %2" : "=v"(a0) : "v"(s[kt][kk * 8 + 0]), "v"(s[kt][kk * 8 + 1]));
        asm("v_cvt_pk_bf16_f32 %0, %1, %2" : "=v"(a1) : "v"(s[kt][kk * 8 + 2]), "v"(s[kt][kk * 8 + 3]));
        asm("v_cvt_pk_bf16_f32 %0, %1, %2" : "=v"(b0) : "v"(s[kt][kk * 8 + 4]), "v"(s[kt][kk * 8 + 5]));
        asm("v_cvt_pk_bf16_f32 %0, %1, %2" : "=v"(b1) : "v"(s[kt][kk * 8 + 6]), "v"(s[kt][kk * 8 + 7]));
        asm("v_permlane32_swap_b32 %0, %1" : "+v"(a0), "+v"(b0));
        asm("v_permlane32_swap_b32 %0, %1" : "+v"(a1), "+v"(b1));
        union { unsigned u[4]; short8 v; } pb;
        pb.u[0] = a0; pb.u[1] = a1; pb.u[2] = b0; pb.u[3] = b1;
#pragma unroll
        for (int dt = 0; dt < 2; dt++) {
          short8 vf = *(const short8*)(&vS[(dt * 32 + l31) * KV_S + kt * 32 + kk * 16 + hi * 8]);
          oacc[dt] = __builtin_amdgcn_mfma_f32_32x32x16_bf16(vf, pb.v, oacc[dt], 0, 0, 0);
        }
      }
    }
  }

  float inv = 1.0f / lsum;
  float* orow = out + ((size_t)b * 4096 + qb0 + l31) * 768 + h * 64;
#pragma unroll
  for (int dt = 0; dt < 2; dt++)
#pragma unroll
    for (int g = 0; g < 4; g++) {
      float4 o;
      o.x = oacc[dt][g * 4 + 0] * inv;
      o.y = oacc[dt][g * 4 + 1] * inv;
      o.z = oacc[dt][g * 4 + 2] * inv;
      o.w = oacc[dt][g * 4 + 3] * inv;
      *(float4*)(orow + dt * 32 + g * 8 + hi * 4) = o;
    }
}

extern "C" void kernel_launch(void* const* d_in, const int* in_sizes, int n_in,
                              void* d_out, int out_size, void* d_ws, size_t ws_size,
                              hipStream_t stream) {
  const float* x = (const float*)d_in[0];      // 4 x 4096 x 768
  const float* w = (const float*)d_in[1];      // 768 x 2304
  const float* bias = (const float*)d_in[2];   // 2304
  float* out = (float*)d_out;                  // 4 x 4096 x 768 fp32

  char* ws = (char*)d_ws;
  unsigned short* xb = (unsigned short*)ws;                       // 16384x768 bf16
  unsigned short* wt = (unsigned short*)(ws + 25165824);          // 2304x768 bf16
  unsigned short* Qb = (unsigned short*)(ws + 28704768);
  unsigned short* Kb = Qb + 12582912;
  unsigned short* Vb = Kb + 12582912;

  hipLaunchKernelGGL(prep_kernel, dim3(14016), dim3(256), 0, stream, x, xb, w, wt);
  hipLaunchKernelGGL(qkv_gemm_kernel, dim3(2304), dim3(256), 0, stream, xb, wt, bias, Qb, Kb, Vb);
  hipLaunchKernelGGL(attn_kernel, dim3(32, 48), dim3(256), 0, stream, Qb, Kb, Vb, out);
}

// Round 17
// 123.984 us; speedup vs baseline: 1.1768x; 1.0267x over previous
//
#include <hip/hip_runtime.h>

typedef __attribute__((ext_vector_type(8))) short short8;
typedef __attribute__((ext_vector_type(16))) float f32x16;
typedef __attribute__((ext_vector_type(4))) float f32x4;

#define L2T 13.287712379549449f  // log2(10000)

__device__ __forceinline__ unsigned short f2bf(float f) {
  unsigned int u = __float_as_uint(f);
  u += 0x7FFFu + ((u >> 16) & 1u);
  return (unsigned short)(u >> 16);
}
__device__ __forceinline__ float bf2f(unsigned short u) {
  return __uint_as_float(((unsigned int)u) << 16);
}

// async global->LDS, 16B per lane; LDS dest = wave-uniform base + lane*16
__device__ __forceinline__ void gload16(const unsigned short* g, unsigned short* l) {
  __builtin_amdgcn_global_load_lds(
      (const __attribute__((address_space(1))) void*)g,
      (__attribute__((address_space(3))) void*)l, 16, 0, 0);
}

// ---------------- prep: cast x fp32->bf16 (blocks 0..12287) + transpose w (rest) -------
__global__ __launch_bounds__(256) void prep_kernel(const float* __restrict__ x,
                                                   unsigned short* __restrict__ xb,
                                                   const float* __restrict__ w,
                                                   unsigned short* __restrict__ wt) {
  __shared__ float tile[32][33];
  int bid = blockIdx.x;
  if (bid < 12288) {
    int i = bid * 256 + threadIdx.x;
    float4 v = ((const float4*)x)[i];
    ushort4 o;
    o.x = f2bf(v.x); o.y = f2bf(v.y); o.z = f2bf(v.z); o.w = f2bf(v.w);
    ((ushort4*)xb)[i] = o;
  } else {
    int b2 = bid - 12288;               // 0..1727
    int n0 = (b2 % 72) * 32, k0 = (b2 / 72) * 32;
    int tx = threadIdx.x & 31, ty = threadIdx.x >> 5;
    for (int i = ty; i < 32; i += 8)
      tile[i][tx] = w[(size_t)(k0 + i) * 2304 + n0 + tx];
    __syncthreads();
    for (int i = ty; i < 32; i += 8)
      wt[(size_t)(n0 + i) * 768 + k0 + tx] = f2bf(tile[tx][i]);
  }
}

// ---------------- QKV GEMM (R16, byte-exact): gload_lds + XOR swizzle + K-rope tail ----
__global__ __launch_bounds__(256) void qkv_gemm_kernel(
    const unsigned short* __restrict__ xb,
    const unsigned short* __restrict__ wt,
    const float* __restrict__ bias,
    unsigned short* __restrict__ Qb,
    unsigned short* __restrict__ Kb,
    unsigned short* __restrict__ Vb) {
  __shared__ unsigned short lA[128 * 64];
  __shared__ unsigned short lB[128 * 64];
  // XCD swizzle: 2304 blocks, 2304%8==0 -> bijective chunked remap (T1)
  int bid = blockIdx.x;
  int swz = (bid & 7) * 288 + (bid >> 3);
  int mt = swz / 18, nt = swz - mt * 18;
  int m0 = mt * 128, n0 = nt * 128;

  int tid = threadIdx.x;
  int lane = tid & 63, wid = tid >> 6;
  int wr = wid >> 1, wc = wid & 1;
  int lr = lane & 15, lg = lane >> 4;
  int lswz = lr & 7;

  int offA[4], offB[4];
  unsigned short* ldsA[4];
  unsigned short* ldsB[4];
#pragma unroll
  for (int i = 0; i < 4; i++) {
    int gi = (wid * 4 + i) * 64 + lane;  // granule id in tile
    int r = gi >> 3;                     // row 0..127
    int gcl = (gi & 7) ^ (r & 7);        // pre-swizzled source col-granule
    offA[i] = (m0 + r) * 768 + gcl * 8;
    offB[i] = (n0 + r) * 768 + gcl * 8;
    ldsA[i] = &lA[(wid * 4 + i) * 512];
    ldsB[i] = &lB[(wid * 4 + i) * 512];
  }

  f32x4 acc[4][4] = {};
  const int rowA = (wr * 64 + lr) * 64;
  const int rowB = (wc * 64 + lr) * 64;

  for (int k0 = 0; k0 < 768; k0 += 64) {
    __syncthreads();
#pragma unroll
    for (int i = 0; i < 4; i++) gload16(xb + offA[i] + k0, ldsA[i]);
#pragma unroll
    for (int i = 0; i < 4; i++) gload16(wt + offB[i] + k0, ldsB[i]);
    __syncthreads();

    short8 af[4][2], bfr[4][2];
#pragma unroll
    for (int ks = 0; ks < 2; ks++) {
      int c = ((ks * 4 + lg) ^ lswz) * 8;
#pragma unroll
      for (int mi = 0; mi < 4; mi++)
        af[mi][ks] = *(const short8*)(&lA[rowA + mi * 1024 + c]);
#pragma unroll
      for (int ni = 0; ni < 4; ni++)
        bfr[ni][ks] = *(const short8*)(&lB[rowB + ni * 1024 + c]);
    }
#pragma unroll
    for (int ks = 0; ks < 2; ks++)
#pragma unroll
      for (int mi = 0; mi < 4; mi++)
#pragma unroll
        for (int ni = 0; ni < 4; ni++)
          acc[mi][ni] = __builtin_amdgcn_mfma_f32_16x16x32_bf16(af[mi][ks], bfr[ni][ks], acc[mi][ni], 0, 0, 0);
  }

  // epilogue: bias; K-rope only (d<32); (mi,reg) outer / ni inner for write combining
  int nb = n0 + wc * 64 + lr;          // ni adds 16
  int which = nb / 768;                 // uniform across lanes and ni
  int idx = nb - which * 768;
  int h = idx >> 6;
  int dbase = idx & 63;                 // d = dbase + ni*16; dbase = lr here
  unsigned short* dst = (which == 0) ? Qb : ((which == 1) ? Kb : Vb);
  bool kv = (which == 1);
  bool isHi = dbase & 1;
  float bvv[4], cinv[4];
#pragma unroll
  for (int ni = 0; ni < 4; ni++) {
    bvv[ni] = bias[nb + ni * 16];
    cinv[ni] = exp2f(-(float)(((dbase + ni * 16) >> 1) & 15) * (L2T / 16.0f));
  }
#pragma unroll
  for (int mi = 0; mi < 4; mi++) {
#pragma unroll
    for (int reg = 0; reg < 4; reg++) {
      int m = m0 + wr * 64 + mi * 16 + lg * 4 + reg;
      int b = m >> 12, t = m & 4095;
      size_t rowoff = (((size_t)(b * 12 + h)) * 4096 + t) * 64;
#pragma unroll
      for (int ni = 0; ni < 4; ni++) {
        float val = acc[mi][ni][reg] + bvv[ni];
        if (kv && ni < 2) {  // K rope, d<32; wave-uniform; partner lane lr^1
          float other = __shfl_xor(val, 1, 64);
          float ang = (float)t * cinv[ni];
          float s, c;
          __sincosf(ang, &s, &c);
          val = isHi ? (val * c + other * s) : (val * c - other * s);
        }
        dst[rowoff + dbase + ni * 16] = f2bf(val);
      }
    }
  }
}

// ---------------- sliding-window attention (R16 body + T14 async-stage split) ----------
// Chunk loop over precomputed valid range [clo,chi): wi=0 -> [2,6), wi=31 -> [0,4),
// else [0,6) (identical to the old kp0-validity predicate). Per chunk:
// barrier -> ds_write regs(c) -> issue global loads(c+1) -> barrier -> compute(c).
// HBM latency of chunk c+1 hides under compute(c) (T14, m214v27 +17%).
#define KV_S 72
__global__ __launch_bounds__(256) void attn_kernel(
    const unsigned short* __restrict__ Qb,
    const unsigned short* __restrict__ Kb,
    const unsigned short* __restrict__ Vb,
    float* __restrict__ out) {
  __shared__ unsigned short kS[64 * KV_S];  // [key][dim]
  __shared__ unsigned short vS[64 * KV_S];  // [dim][key]
  int bidx = blockIdx.x;
  int wi = ((bidx & 7) << 2) | (bidx >> 3);  // bijective window remap (L2 locality)
  int bh = blockIdx.y;
  int b = bh / 12, h = bh - b * 12;
  int tid = threadIdx.x, lane = tid & 63, wid = tid >> 6;
  int l31 = lane & 31, hi = lane >> 5;

  int qb0 = wi * 128 + wid * 32;
  const unsigned short* Qrow = Qb + ((size_t)bh * 4096 + qb0) * 64;
  short8 qf[4];
#pragma unroll
  for (int kk = 0; kk < 4; kk++)
    qf[kk] = *(const short8*)(Qrow + (size_t)l31 * 64 + kk * 16 + hi * 8);

  // RoPE on Q frags kk=0,1 (dims<32); pairs in-lane; t = qb0 + l31 (R14/R16-proven)
  {
    int t = qb0 + l31;
#pragma unroll
    for (int kk = 0; kk < 2; kk++) {
      unsigned short* e = (unsigned short*)&qf[kk];
      int j0 = kk * 8 + hi * 4;
#pragma unroll
      for (int p = 0; p < 4; p++) {
        float invf = exp2f(-(float)(j0 + p) * (L2T / 16.0f));
        float ang = (float)t * invf;
        float s, c;
        __sincosf(ang, &s, &c);
        float a = bf2f(e[2 * p]), b2 = bf2f(e[2 * p + 1]);
        e[2 * p] = f2bf(a * c - b2 * s);
        e[2 * p + 1] = f2bf(b2 * c + a * s);
      }
    }
  }

  f32x16 oacc[2];
#pragma unroll
  for (int dt = 0; dt < 2; dt++)
#pragma unroll
    for (int r = 0; r < 16; r++) oacc[dt][r] = 0.0f;
  float mrow = -1e30f, lsum = 0.0f;

  const unsigned short* Kbase = Kb + (size_t)bh * 4096 * 64;
  const unsigned short* Vbase = Vb + (size_t)bh * 4096 * 64;

  int vk = tid & 63;
  int vq = tid >> 6;
  int kk0 = tid >> 3, kk1 = (tid + 256) >> 3, kco = (tid & 7) * 8;

  int clo = (wi == 0) ? 2 : 0;
  int chi = (wi == 31) ? 4 : 6;
  int kpbase = (wi - 1) * 128;

  uint4 kreg0, kreg1, vreg0, vreg1;
  {  // preload first chunk
    int kp0 = kpbase + clo * 64;
    kreg0 = *(const uint4*)(Kbase + (size_t)(kp0 + kk0) * 64 + kco);
    kreg1 = *(const uint4*)(Kbase + (size_t)(kp0 + kk1) * 64 + kco);
    const unsigned short* vp = Vbase + (size_t)(kp0 + vk) * 64 + vq * 16;
    vreg0 = *(const uint4*)(vp);
    vreg1 = *(const uint4*)(vp + 8);
  }

  for (int c = clo; c < chi; c++) {
    __syncthreads();  // prior chunk's compute done with LDS
    // write chunk c from regs (compiler waits vmcnt for reg deps)
    *(uint4*)(&kS[kk0 * KV_S + kco]) = kreg0;
    *(uint4*)(&kS[kk1 * KV_S + kco]) = kreg1;
    {
      const unsigned short* e = (const unsigned short*)&vreg0;
#pragma unroll
      for (int i = 0; i < 8; i++) vS[(vq * 16 + i) * KV_S + vk] = e[i];
      e = (const unsigned short*)&vreg1;
#pragma unroll
      for (int i = 0; i < 8; i++) vS[(vq * 16 + 8 + i) * KV_S + vk] = e[i];
    }
    // issue next chunk's loads now; they fly during compute(c)
    if (c + 1 < chi) {
      int kp0 = kpbase + (c + 1) * 64;
      kreg0 = *(const uint4*)(Kbase + (size_t)(kp0 + kk0) * 64 + kco);
      kreg1 = *(const uint4*)(Kbase + (size_t)(kp0 + kk1) * 64 + kco);
      const unsigned short* vp = Vbase + (size_t)(kp0 + vk) * 64 + vq * 16;
      vreg0 = *(const uint4*)(vp);
      vreg1 = *(const uint4*)(vp + 8);
    }
    __syncthreads();  // LDS ready

    f32x16 s[2];
#pragma unroll
    for (int kt = 0; kt < 2; kt++) {
      f32x16 acc;
#pragma unroll
      for (int r = 0; r < 16; r++) acc[r] = 0.0f;
#pragma unroll
      for (int kk = 0; kk < 4; kk++) {
        short8 kf = *(const short8*)(&kS[(kt * 32 + l31) * KV_S + kk * 16 + hi * 8]);
        acc = __builtin_amdgcn_mfma_f32_32x32x16_bf16(kf, qf[kk], acc, 0, 0, 0);
      }
      s[kt] = acc;
    }
    // 1/8 softmax scale post-MFMA (R14/R16-proven exact)
#pragma unroll
    for (int kt = 0; kt < 2; kt++)
#pragma unroll
      for (int r = 0; r < 16; r++) s[kt][r] *= 0.125f;

    float vmax = -1e30f;
#pragma unroll
    for (int kt = 0; kt < 2; kt++)
#pragma unroll
      for (int r = 0; r < 16; r++) vmax = fmaxf(vmax, s[kt][r]);
    vmax = fmaxf(vmax, __shfl_xor(vmax, 32, 64));
    float mnew = fmaxf(mrow, vmax);
    float corr = __expf(mrow - mnew);
    mrow = mnew;
    float rs = 0.0f;
#pragma unroll
    for (int kt = 0; kt < 2; kt++)
#pragma unroll
      for (int r = 0; r < 16; r++) {
        float p = __expf(s[kt][r] - mnew);
        s[kt][r] = p;
        rs += p;
      }
    rs += __shfl_xor(rs, 32, 64);
    lsum = lsum * corr + rs;
#pragma unroll
    for (int dt = 0; dt < 2; dt++)
#pragma unroll
      for (int r = 0; r < 16; r++) oacc[dt][r] *= corr;

#pragma unroll
    for (int kt = 0; kt < 2; kt++) {
#pragma unroll
      for (int kk = 0; kk < 2; kk++) {
        unsigned a0, a1, b0, b1;
        asm("v_cvt_pk_bf16_f32 %0, %1, %2" : "=v"(a0) : "v"(s[kt][kk * 8 + 0]), "v"(s[kt][kk * 8 + 1]));
        asm("v_cvt_pk_bf16_f32 %0, %1, %2" : "=v"(a1) : "v"(s[kt][kk * 8 + 2]), "v"(s[kt][kk * 8 + 3]));
        asm("v_cvt_pk_bf16_f32 %0, %1, %2" : "=v"(b0) : "v"(s[kt][kk * 8 + 4]), "v"(s[kt][kk * 8 + 5]));
        asm("v_cvt_pk_bf16_f32 %0, %1, %2" : "=v"(b1) : "v"(s[kt][kk * 8 + 6]), "v"(s[kt][kk * 8 + 7]));
        asm("v_permlane32_swap_b32 %0, %1" : "+v"(a0), "+v"(b0));
        asm("v_permlane32_swap_b32 %0, %1" : "+v"(a1), "+v"(b1));
        union { unsigned u[4]; short8 v; } pb;
        pb.u[0] = a0; pb.u[1] = a1; pb.u[2] = b0; pb.u[3] = b1;
#pragma unroll
        for (int dt = 0; dt < 2; dt++) {
          short8 vf = *(const short8*)(&vS[(dt * 32 + l31) * KV_S + kt * 32 + kk * 16 + hi * 8]);
          oacc[dt] = __builtin_amdgcn_mfma_f32_32x32x16_bf16(vf, pb.v, oacc[dt], 0, 0, 0);
        }
      }
    }
  }

  float inv = 1.0f / lsum;
  float* orow = out + ((size_t)b * 4096 + qb0 + l31) * 768 + h * 64;
#pragma unroll
  for (int dt = 0; dt < 2; dt++)
#pragma unroll
    for (int g = 0; g < 4; g++) {
      float4 o;
      o.x = oacc[dt][g * 4 + 0] * inv;
      o.y = oacc[dt][g * 4 + 1] * inv;
      o.z = oacc[dt][g * 4 + 2] * inv;
      o.w = oacc[dt][g * 4 + 3] * inv;
      *(float4*)(orow + dt * 32 + g * 8 + hi * 4) = o;
    }
}

extern "C" void kernel_launch(void* const* d_in, const int* in_sizes, int n_in,
                              void* d_out, int out_size, void* d_ws, size_t ws_size,
                              hipStream_t stream) {
  const float* x = (const float*)d_in[0];      // 4 x 4096 x 768
  const float* w = (const float*)d_in[1];      // 768 x 2304
  const float* bias = (const float*)d_in[2];   // 2304
  float* out = (float*)d_out;                  // 4 x 4096 x 768 fp32

  char* ws = (char*)d_ws;
  unsigned short* xb = (unsigned short*)ws;                       // 16384x768 bf16
  unsigned short* wt = (unsigned short*)(ws + 25165824);          // 2304x768 bf16
  unsigned short* Qb = (unsigned short*)(ws + 28704768);
  unsigned short* Kb = Qb + 12582912;
  unsigned short* Vb = Kb + 12582912;

  hipLaunchKernelGGL(prep_kernel, dim3(14016), dim3(256), 0, stream, x, xb, w, wt);
  hipLaunchKernelGGL(qkv_gemm_kernel, dim3(2304), dim3(256), 0, stream, xb, wt, bias, Qb, Kb, Vb);
  hipLaunchKernelGGL(attn_kernel, dim3(32, 48), dim3(256), 0, stream, Qb, Kb, Vb, out);
}